// Round 1
// baseline (118.455 us; speedup 1.0000x reference)
//
#include <hip/hip_runtime.h>
#include <stdint.h>

// Sampler: temperature -> top-k -> top-p -> softmax -> multinomial (threefry)
// One block per row. Two global passes (histogram radix-bin, then candidate
// collection); all remaining work on ~O(100) survivors in LDS.

#define BLOCK 512
#define BINS  4096
#define CAP   1024
#define TOPP  0.9f

// Order-preserving float -> uint map (ascending float == ascending uint)
__device__ __forceinline__ unsigned orderKey(float x) {
  unsigned u = __float_as_uint(x);
  return (u & 0x80000000u) ? ~u : (u | 0x80000000u);
}

// JAX threefry2x32 (20 rounds), exact.
__device__ __forceinline__ void threefry2x32(unsigned k0, unsigned k1,
                                             unsigned x0, unsigned x1,
                                             unsigned &o0, unsigned &o1) {
  unsigned k2 = k0 ^ k1 ^ 0x1BD11BDAu;
  x0 += k0; x1 += k1;
#define TFR(rr) { x0 += x1; x1 = (x1 << (rr)) | (x1 >> (32 - (rr))); x1 ^= x0; }
  TFR(13) TFR(15) TFR(26) TFR(6)
  x0 += k1; x1 += k2 + 1u;
  TFR(17) TFR(29) TFR(16) TFR(24)
  x0 += k2; x1 += k0 + 2u;
  TFR(13) TFR(15) TFR(26) TFR(6)
  x0 += k0; x1 += k1 + 3u;
  TFR(17) TFR(29) TFR(16) TFR(24)
  x0 += k1; x1 += k2 + 4u;
  TFR(13) TFR(15) TFR(26) TFR(6)
  x0 += k2; x1 += k0 + 5u;
#undef TFR
  o0 = x0; o1 = x1;
}

__global__ __launch_bounds__(BLOCK) void Sampler_28845000360542_kernel(
    const float* __restrict__ logits, const int* __restrict__ topk_ptr,
    int* __restrict__ out, int V, int B) {
  __shared__ unsigned hist[BINS];
  __shared__ float    cval[CAP];
  __shared__ int      cidx[CAP];
  __shared__ float    sval[CAP];
  __shared__ int      sidx[CAP];
  __shared__ unsigned psum[BLOCK];
  __shared__ short    ord[CAP];
  __shared__ unsigned s_cnt;
  __shared__ int      s_binLo;
  __shared__ int      s_ns;
  __shared__ int      s_K;
  __shared__ float    s_S2;
  __shared__ float    s_r;

  const int tid = threadIdx.x;
  const int row = blockIdx.x;
  const float* __restrict__ rp = logits + (size_t)row * (size_t)V;
  const float4* __restrict__ rp4 = (const float4*)rp;
  const int V4 = V >> 2;

  int k = topk_ptr[0];
  if (k < 1) k = 1;
  if (k > V) k = V;

  // ---- Phase A: histogram on top 12 bits of order key ----
  for (int i = tid; i < BINS; i += BLOCK) hist[i] = 0u;
  if (tid == 0) s_cnt = 0u;
  __syncthreads();

  for (int i = tid; i < V4; i += BLOCK) {
    float4 v = rp4[i];
    atomicAdd(&hist[orderKey(v.x) >> 20], 1u);
    atomicAdd(&hist[orderKey(v.y) >> 20], 1u);
    atomicAdd(&hist[orderKey(v.z) >> 20], 1u);
    atomicAdd(&hist[orderKey(v.w) >> 20], 1u);
  }
  for (int i = (V4 << 2) + tid; i < V; i += BLOCK)
    atomicAdd(&hist[orderKey(rp[i]) >> 20], 1u);
  __syncthreads();

  // ---- Phase B: find bin containing the k-th largest ----
  {
    const int C = BINS / BLOCK;  // 8 bins per thread
    unsigned s = 0;
#pragma unroll
    for (int j = 0; j < C; ++j) s += hist[tid * C + j];
    psum[tid] = s;
  }
  __syncthreads();

  if (tid == 0) {
    const int C = BINS / BLOCK;
    unsigned cum = 0;
    int chunk = 0;
    for (int t = BLOCK - 1; t >= 0; --t) {
      if (cum + psum[t] >= (unsigned)k) { chunk = t; break; }
      cum += psum[t];
    }
    int bstar = chunk * C;
    for (int b = chunk * C + C - 1; b >= chunk * C; --b) {
      if (cum + hist[b] >= (unsigned)k) { bstar = b; break; }
      cum += hist[b];
    }
    unsigned nCol = cum + hist[bstar];
    int bLo = bstar;
    // tie-safety: one extra bin below (covers temperature-division value
    // collapse across a bin boundary) when it fits the buffer
    if (bstar > 0 && nCol + hist[bstar - 1] <= (unsigned)CAP) bLo = bstar - 1;
    s_binLo = bLo;
  }
  __syncthreads();

  // ---- Phase C: collect candidates >= bin floor ----
  const unsigned binLo = (unsigned)s_binLo;
  for (int i = tid; i < V4; i += BLOCK) {
    float4 v = rp4[i];
    float vv[4] = {v.x, v.y, v.z, v.w};
#pragma unroll
    for (int c = 0; c < 4; ++c) {
      if ((orderKey(vv[c]) >> 20) >= binLo) {
        unsigned pos = atomicAdd(&s_cnt, 1u);
        if (pos < CAP) { cval[pos] = vv[c]; cidx[pos] = (i << 2) + c; }
      }
    }
  }
  for (int i = (V4 << 2) + tid; i < V; i += BLOCK) {
    float x = rp[i];
    if ((orderKey(x) >> 20) >= binLo) {
      unsigned pos = atomicAdd(&s_cnt, 1u);
      if (pos < CAP) { cval[pos] = x; cidx[pos] = i; }
    }
  }
  __syncthreads();

  int n = (int)s_cnt;
  if (n > CAP) n = CAP;

  // ---- Phase D: temperature scale, then rank-sort (value desc, idx asc) ----
  for (int i = tid; i < n; i += BLOCK) cval[i] = cval[i] / 0.8f;  // IEEE div, matches ref
  __syncthreads();
  for (int i = tid; i < n; i += BLOCK) {
    float v = cval[i];
    int   id = cidx[i];
    int   rk = 0;
    for (int j = 0; j < n; ++j) {
      float vj = cval[j];
      rk += (vj > v) || (vj == v && cidx[j] < id);
    }
    sval[rk] = v;
    sidx[rk] = id;
  }
  __syncthreads();

  // ---- Phase E: top-k survivor count (keep ties at the k-th value) ----
  if (tid == 0) {
    int ns = (n < k) ? n : k;
    float kv = sval[ns - 1];
    while (ns < n && sval[ns] == kv) ++ns;
    s_ns = ns;
  }
  __syncthreads();
  const int ns = s_ns;

  // ---- Phase F: exp(v - max) in parallel (reuse cval as e[]) ----
  const float m = sval[0];
  for (int i = tid; i < ns; i += BLOCK) cval[i] = expf(sval[i] - m);
  __syncthreads();

  // ---- Phase G: top-p keep-prefix + RNG (serial, deterministic order) ----
  if (tid == 0) {
    float S = 0.f;
    for (int i = 0; i < ns; ++i) S += cval[i];
    float c = 0.f;
    int K = ns;
    for (int i = 0; i < ns; ++i) {
      if (i > 0 && c > TOPP) { K = i; break; }  // remove[i] = cdf[i-1] > p
      c += cval[i] / S;                          // per-element div then add, like ref
    }
    float S2 = 0.f;
    for (int i = 0; i < K; ++i) S2 += cval[i];
    s_K = K;
    s_S2 = S2;

    // r = uniform from fold_in(key(0), 1), partitionable threefry path:
    // key' = tf((0,0),(0,1)); bits[row] = o0 ^ o1 of tf(key', hi=0, lo=row)
    unsigned kk0, kk1, o0, o1;
    threefry2x32(0u, 0u, 0u, 1u, kk0, kk1);
    threefry2x32(kk0, kk1, 0u, (unsigned)row, o0, o1);
    unsigned bits = o0 ^ o1;
    float r = __uint_as_float((bits >> 9) | 0x3F800000u) - 1.0f;
    s_r = (r < 0.f) ? 0.f : r;
    (void)B;
  }
  __syncthreads();
  const int K = s_K;

  // ---- Phase H: rank kept tokens by original index ----
  for (int i = tid; i < K; i += BLOCK) {
    int id = sidx[i];
    int rk = 0;
    for (int j = 0; j < K; ++j) rk += (sidx[j] < id);
    ord[rk] = (short)i;
  }
  __syncthreads();

  // ---- Phase I: inverse-CDF sample in original-index order ----
  if (tid == 0) {
    const float S2 = s_S2;
    const float rr = s_r;
    float c = 0.f;
    int ans = V;  // matches sum(cdf <= r) == V when r beyond total mass
    for (int t = 0; t < K; ++t) {
      int i = ord[t];
      c += cval[i] / S2;
      if (c > rr) { ans = sidx[i]; break; }
    }
    out[row] = ans;
  }
}

extern "C" void kernel_launch(void* const* d_in, const int* in_sizes, int n_in,
                              void* d_out, int out_size, void* d_ws, size_t ws_size,
                              hipStream_t stream) {
  const float* logits = (const float*)d_in[0];
  const int*   topk   = (const int*)d_in[1];
  int*         out    = (int*)d_out;
  const int B = out_size;              // 256 rows, one int per row
  const int V = in_sizes[0] / B;       // 50257
  hipLaunchKernelGGL(Sampler_28845000360542_kernel, dim3(B), dim3(BLOCK), 0,
                     stream, logits, topk, out, V, B);
}